// Round 10
// baseline (211.523 us; speedup 1.0000x reference)
//
#include <hip/hip_runtime.h>
#include <cstdint>
#include <cstddef>

// Problem constants (B, C, N fixed by the reference)
#define KB_  8
#define KC_  512
#define KC2_ 256
#define KN_  2048

typedef __attribute__((ext_vector_type(8))) __bf16 bf16x8;
typedef __attribute__((ext_vector_type(8))) unsigned short u16x8;
typedef __attribute__((ext_vector_type(4))) float f32x4;

__device__ __forceinline__ unsigned short f2bf(float f) {
  union { float f; unsigned u; } x; x.f = f;
  unsigned r = x.u + 0x7fffu + ((x.u >> 16) & 1u);  // RNE (finite values only)
  return (unsigned short)(r >> 16);
}
__device__ __forceinline__ float bf2f(unsigned short h) {
  union { unsigned u; float f; } x; x.u = ((unsigned)h) << 16;
  return x.f;
}

// async global->LDS, 16B per lane; LDS dest = wave-uniform base + lane*16 (linear!)
#define GLD16(g, l) __builtin_amdgcn_global_load_lds( \
    (__attribute__((address_space(1))) void*)(g),     \
    (__attribute__((address_space(3))) void*)(l), 16, 0, 0)

// counted-vmcnt barrier pair (T4): wait only the CURRENT buffer's 8 loads;
// next-tile loads stay in flight across the barrier.
#define WAIT_VM8()  asm volatile("s_waitcnt vmcnt(8)" ::: "memory")
#define WAIT_VM0()  asm volatile("s_waitcnt vmcnt(0)" ::: "memory")
#define BARRIER()   __builtin_amdgcn_s_barrier()

// bijective XCD-aware block swizzle (nb % 8 == 0 for all our grids)
__device__ __forceinline__ void xcd_swizzle(int& bx, int& by, int& bz) {
  const int gx = gridDim.x, gy = gridDim.y;
  const int nb = gx * gy * (int)gridDim.z;
  int f = ((int)blockIdx.z * gy + (int)blockIdx.y) * gx + (int)blockIdx.x;
  if ((nb & 7) == 0) f = (f & 7) * (nb >> 3) + (f >> 3);
  const int gxy = gx * gy;
  bz = f / gxy; int rem = f - bz * gxy;
  by = rem / gx; bx = rem - by * gx;
}

// ---------------- weight fp32 -> bf16 convert (single) ----------------
__global__ __launch_bounds__(256) void cvt_kernel(const float* __restrict__ in,
                                                  unsigned short* __restrict__ out, int n) {
  int i = (blockIdx.x * 256 + threadIdx.x) * 4;
  if (i >= n) return;
  float4 f = *(const float4*)(in + i);
  ushort4 u = { f2bf(f.x), f2bf(f.y), f2bf(f.z), f2bf(f.w) };
  *(ushort4*)(out + i) = u;
}

// ---------------- weight fp32 -> bf16 hi/lo pair ----------------
__global__ __launch_bounds__(256) void cvt_pair_kernel(const float* __restrict__ in,
                                                       unsigned short* __restrict__ hi,
                                                       unsigned short* __restrict__ lo, int n) {
  int i = (blockIdx.x * 256 + threadIdx.x) * 4;
  if (i >= n) return;
  float4 f = *(const float4*)(in + i);
  ushort4 h = { f2bf(f.x), f2bf(f.y), f2bf(f.z), f2bf(f.w) };
  ushort4 l = { f2bf(f.x - bf2f(h.x)), f2bf(f.y - bf2f(h.y)),
                f2bf(f.z - bf2f(h.z)), f2bf(f.w - bf2f(h.w)) };
  *(ushort4*)(hi + i) = h;
  *(ushort4*)(lo + i) = l;
}

// ---------------- tiled transpose: fp32 [R][Cc] -> bf16 hi/lo [Cc][R] ----------------
__global__ __launch_bounds__(256) void transpose_pair_kernel(const float* __restrict__ in,
                                                             long sIn,
                                                             unsigned short* __restrict__ hi,
                                                             unsigned short* __restrict__ lo,
                                                             long sOut, int R, int Cc) {
  int b = blockIdx.z;
  const float* I = in + (size_t)b * sIn;
  __shared__ float tile[64][65];
  int t = threadIdx.x;
  int r0 = blockIdx.y * 64, c0 = blockIdx.x * 64;
#pragma unroll
  for (int k = 0; k < 4; k++) {
    int vi = k * 256 + t, rr = vi >> 4, cv = vi & 15;
    float4 f = *(const float4*)&I[(size_t)(r0 + rr) * Cc + c0 + cv * 4];
    tile[rr][cv * 4 + 0] = f.x; tile[rr][cv * 4 + 1] = f.y;
    tile[rr][cv * 4 + 2] = f.z; tile[rr][cv * 4 + 3] = f.w;
  }
  __syncthreads();
#pragma unroll
  for (int k = 0; k < 4; k++) {
    int vi = k * 256 + t, cc = vi >> 4, rv = vi & 15;
    float f0 = tile[rv * 4 + 0][cc], f1 = tile[rv * 4 + 1][cc];
    float f2 = tile[rv * 4 + 2][cc], f3 = tile[rv * 4 + 3][cc];
    ushort4 h = { f2bf(f0), f2bf(f1), f2bf(f2), f2bf(f3) };
    ushort4 l = { f2bf(f0 - bf2f(h.x)), f2bf(f1 - bf2f(h.y)),
                  f2bf(f2 - bf2f(h.z)), f2bf(f3 - bf2f(h.w)) };
    size_t o = (size_t)b * sOut + (size_t)(c0 + cc) * R + r0 + rv * 4;
    *(ushort4*)&hi[o] = h;
    *(ushort4*)&lo[o] = l;
  }
}

// ---------------- rsv[b][n] = 1 / sum_k rowpart[b][n][k] ----------------
__global__ __launch_bounds__(256) void rowreduce_kernel(const float* __restrict__ rowpart,
                                                        float* __restrict__ rsv) {
  int idx = blockIdx.x * 256 + threadIdx.x;  // 8*2048 rows
  const float* p = rowpart + (size_t)idx * 32;
  float s = 0.f;
#pragma unroll
  for (int k = 0; k < 32; k++) s += p[k];
  rsv[idx] = 1.0f / s;
}

// ---------------- x_v[b][c][n] *= rsv[b][n] (in-place, bf16) ----------------
__global__ __launch_bounds__(256) void xvscale_kernel(unsigned short* __restrict__ xv,
                                                      const float* __restrict__ rsv) {
  size_t idx = ((size_t)blockIdx.x * 256 + threadIdx.x) * 8;
  int n = (int)(idx & (KN_ - 1));
  int b = (int)(idx >> 19);  // 2048*256 = 2^19 elems per batch
  u16x8 u = *(const u16x8*)&xv[idx];
  const float* R = rsv + (size_t)b * KN_ + n;
  float4 r0 = *(const float4*)R;
  float4 r1 = *(const float4*)(R + 4);
  u16x8 o;
  o[0] = f2bf(bf2f(u[0]) * r0.x); o[1] = f2bf(bf2f(u[1]) * r0.y);
  o[2] = f2bf(bf2f(u[2]) * r0.z); o[3] = f2bf(bf2f(u[3]) * r0.w);
  o[4] = f2bf(bf2f(u[4]) * r1.x); o[5] = f2bf(bf2f(u[5]) * r1.y);
  o[6] = f2bf(bf2f(u[6]) * r1.z); o[7] = f2bf(bf2f(u[7]) * r1.w);
  *(u16x8*)&xv[idx] = o;
}

// ---------------- denom[b][m] = sum_n uT[b][m][n] * rsv[b][n] ----------------
__global__ __launch_bounds__(256) void denom_kernel(const unsigned short* __restrict__ uT,
                                                    const float* __restrict__ rsv,
                                                    float* __restrict__ denom) {
  int b = blockIdx.y;
  int m = blockIdx.x * 4 + (threadIdx.x >> 6);
  int lane = threadIdx.x & 63;
  const unsigned short* U = uT + ((size_t)b * KN_ + m) * KN_;
  const float* R = rsv + (size_t)b * KN_;
  float s = 0.f;
#pragma unroll
  for (int c = 0; c < 4; c++) {
    int n = c * 512 + lane * 8;
    u16x8 u = *(const u16x8*)&U[n];
    float4 r0 = *(const float4*)&R[n];
    float4 r1 = *(const float4*)&R[n + 4];
    s += bf2f(u[0]) * r0.x + bf2f(u[1]) * r0.y + bf2f(u[2]) * r0.z + bf2f(u[3]) * r0.w;
    s += bf2f(u[4]) * r1.x + bf2f(u[5]) * r1.y + bf2f(u[6]) * r1.z + bf2f(u[7]) * r1.w;
  }
#pragma unroll
  for (int o = 32; o > 0; o >>= 1) s += __shfl_xor(s, o, 64);
  if (lane == 0) denom[(size_t)b * KN_ + m] = s;
}

// ---------------- energy kernel: 256x256 tile, 8 waves, BK=32, 2-phase dbuf
// (counted vmcnt); split hi/lo GEMM + exp + transpose + row-partials ----
__global__ __launch_bounds__(512, 2) void energy_kernel(
    const unsigned short* __restrict__ Ahi, const unsigned short* __restrict__ Alo,
    const unsigned short* __restrict__ Bhi, const unsigned short* __restrict__ Blo,
    unsigned short* __restrict__ uT, float* __restrict__ rowpart) {
  int bx, by, b;
  xcd_swizzle(bx, by, b);  // grid (8,8,8): each XCD owns one batch
  Ahi += (size_t)b * KN_ * KC2_; Alo += (size_t)b * KN_ * KC2_;
  Bhi += (size_t)b * KN_ * KC2_; Blo += (size_t)b * KN_ * KC2_;
  const int m0 = by * 256;  // rows = n (query idx)
  const int n0 = bx * 256;  // cols = m (key idx)
  __shared__ __align__(16) char smem[131072];  // 2 phases x 64KB; reused for transpose
  const int t = threadIdx.x, lane = t & 63, w = t >> 6;  // 8 waves
  const int wr = w >> 2, wc = w & 3;       // wave grid 2 (m) x 4 (n)
  const int srow = t >> 2;                 // 0..127
  const int scol = (((t & 3) ^ ((srow >> 1) & 3)) * 8);   // pre-swizzled k-chunk
  const int lr = lane & 15, lk = (lane >> 4) * 8;
  const int rsw = ((lr >> 1) & 3) << 4;                   // read-side XOR (bytes)

  auto STAGE = [&](char* dst, int kt) {
    const size_t ga = (size_t)(m0 + srow) * KC2_ + kt + scol;
    const size_t gb = (size_t)(n0 + srow) * KC2_ + kt + scol;
    GLD16(Ahi + ga, dst + 0 + w * 1024);                    // A-hi rows 0-127
    GLD16(Ahi + ga + (size_t)128 * KC2_, dst + 8192 + w * 1024);   // rows 128-255
    GLD16(Alo + ga, dst + 16384 + w * 1024);
    GLD16(Alo + ga + (size_t)128 * KC2_, dst + 24576 + w * 1024);
    GLD16(Bhi + gb, dst + 32768 + w * 1024);
    GLD16(Bhi + gb + (size_t)128 * KC2_, dst + 40960 + w * 1024);
    GLD16(Blo + gb, dst + 49152 + w * 1024);
    GLD16(Blo + gb + (size_t)128 * KC2_, dst + 57344 + w * 1024);
  };

  f32x4 acc[8][4];
  const f32x4 z = {0.f, 0.f, 0.f, 0.f};
#pragma unroll
  for (int i = 0; i < 8; i++)
#pragma unroll
    for (int j = 0; j < 4; j++) acc[i][j] = z;

  STAGE(smem, 0);
  for (int kt8 = 0; kt8 < 8; kt8++) {
    char* cur = smem + (kt8 & 1) * 65536;
    char* nxt = smem + ((kt8 & 1) ^ 1) * 65536;
    if (kt8 < 7) {
      STAGE(nxt, (kt8 + 1) * 32);  // +8 loads in flight per wave
      WAIT_VM8();                  // wait only cur's 8 (oldest)
    } else {
      WAIT_VM0();
    }
    BARRIER();
    bf16x8 bh[4], bl[4];
#pragma unroll
    for (int j = 0; j < 4; j++) {
      int ro = (wc * 64 + j * 16 + lr) * 64 + ((lk * 2) ^ rsw);
      bh[j] = *(const bf16x8*)(cur + 32768 + ro);
      bl[j] = *(const bf16x8*)(cur + 49152 + ro);
    }
#pragma unroll
    for (int i = 0; i < 8; i++) {
      int ro = (wr * 128 + i * 16 + lr) * 64 + ((lk * 2) ^ rsw);
      bf16x8 ah = *(const bf16x8*)(cur + ro);
      bf16x8 al = *(const bf16x8*)(cur + 16384 + ro);
#pragma unroll
      for (int j = 0; j < 4; j++) {
        acc[i][j] = __builtin_amdgcn_mfma_f32_16x16x32_bf16(al, bh[j], acc[i][j], 0, 0, 0);
        acc[i][j] = __builtin_amdgcn_mfma_f32_16x16x32_bf16(ah, bl[j], acc[i][j], 0, 0, 0);
        acc[i][j] = __builtin_amdgcn_mfma_f32_16x16x32_bf16(ah, bh[j], acc[i][j], 0, 0, 0);
      }
    }
    BARRIER();
  }

  // ---- u = exp(E - 40) ----
#pragma unroll
  for (int i = 0; i < 8; i++)
#pragma unroll
    for (int j = 0; j < 4; j++)
#pragma unroll
      for (int r = 0; r < 4; r++) acc[i][j][r] = __expf(acc[i][j][r] - 40.f);

  // ---- partial row sums (wave covers 64 cols; reduce over 16 lanes) ----
#pragma unroll
  for (int i = 0; i < 8; i++) {
#pragma unroll
    for (int r = 0; r < 4; r++) {
      float s = acc[i][0][r] + acc[i][1][r] + acc[i][2][r] + acc[i][3][r];
      s += __shfl_xor(s, 1, 64); s += __shfl_xor(s, 2, 64);
      s += __shfl_xor(s, 4, 64); s += __shfl_xor(s, 8, 64);
      if ((lane & 15) == 0) {
        int row = m0 + wr * 128 + i * 16 + ((lane >> 4) << 2) + r;
        rowpart[((size_t)b * KN_ + row) * 32 + bx * 4 + wc] = s;
      }
    }
  }

  // ---- transpose to uT via LDS (256 km-rows x 512B, XOR-swizzled) ----
#pragma unroll
  for (int i = 0; i < 8; i++) {
#pragma unroll
    for (int j = 0; j < 4; j++) {
#pragma unroll
      for (int r2 = 0; r2 < 4; r2 += 2) {
        int qn = wr * 128 + i * 16 + ((lane >> 4) << 2) + r2;
        int km = wc * 64 + j * 16 + lr;
        unsigned pk = (unsigned)f2bf(acc[i][j][r2]) |
                      ((unsigned)f2bf(acc[i][j][r2 + 1]) << 16);
        int a = (km << 9) + ((qn << 1) ^ ((km & 15) << 4));
        *(unsigned*)(smem + a) = pk;
      }
    }
  }
  __syncthreads();
  // 16 lanes cooperate per uT row -> 256B coalesced bursts
  {
    int kmb = t >> 4, chunk = t & 15;
#pragma unroll
    for (int it = 0; it < 8; it++) {
      int km = kmb + it * 32;
      size_t gbase = ((size_t)b * KN_ + (n0 + km)) * KN_ + m0;
#pragma unroll
      for (int h = 0; h < 2; h++) {
        int c = h * 16 + chunk;
        int a = (km << 9) + ((c << 4) ^ ((km & 15) << 4));
        *(bf16x8*)&uT[gbase + c * 8] = *(const bf16x8*)(smem + a);
      }
    }
  }
}

// ---------------- epilogue variants ----------------
enum { EPI_PAIR = 0, EPI_BIAS = 1, EPI_XRT = 3, EPI_FINAL = 4 };

struct EpiParams {
  const float* bias;
  const float* xf;  long xf_stride;
  const float* scale; long scale_stride;
  const float* gamma; const float* beta; const float* mean; const float* var;
};

// ============== unified MFMA GEMM core, 128x128 tile, BK=64, 2-phase dbuf
// with counted vmcnt; segmented-K: if seg>0 (K=3*seg): A'=[A0|A1|A0], B'=[B0|B0|B1]. ====
template<int EPI>
__device__ __forceinline__ void gemm_core(
    char* __restrict__ smem, int bx, int by, int b,
    const unsigned short* __restrict__ A0, const unsigned short* __restrict__ A1,
    long sA, int lda, int seg,
    const unsigned short* __restrict__ B0, const unsigned short* __restrict__ B1,
    long sB, int ldb,
    void* __restrict__ Cv, void* __restrict__ Cv2, long sC, int ldc, int K,
    const EpiParams& ep) {
  A0 += (size_t)b * sA; A1 += (size_t)b * sA;
  B0 += (size_t)b * sB; B1 += (size_t)b * sB;
  const int m0 = by * 128, n0 = bx * 128;
  const int t = threadIdx.x, lane = t & 63, w = t >> 6;
  const int wr = w >> 1, wc = w & 1;
  const int srow = t >> 2;
  const int scol = (((t & 3) ^ ((srow >> 1) & 3)) * 8);   // pre-swizzled k-chunk
  const int lr = lane & 15, lk = (lane >> 4) * 8;
  const int rsw = ((lr >> 1) & 3) << 4;                   // read-side XOR (bytes)

  auto STAGE = [&](char* dst, int kt) {
    int s = seg ? ((kt >= seg) + (kt >= 2 * seg)) : 0;
    int kl = kt - s * seg;
    const unsigned short* Ab = (s == 1) ? A1 : A0;
    const unsigned short* Bb = (s == 2) ? B1 : B0;
    const unsigned short* gA = Ab + (size_t)(m0 + srow) * lda + kl + scol;
    const unsigned short* gB = Bb + (size_t)(n0 + srow) * ldb + kl + scol;
    GLD16(gA, dst + w * 1024);                         // A k0
    GLD16(gA + (size_t)64 * lda, dst + 4096 + w * 1024);
    GLD16(gA + 32, dst + 8192 + w * 1024);             // A k1
    GLD16(gA + (size_t)64 * lda + 32, dst + 12288 + w * 1024);
    GLD16(gB, dst + 16384 + w * 1024);                 // B k0
    GLD16(gB + (size_t)64 * ldb, dst + 20480 + w * 1024);
    GLD16(gB + 32, dst + 24576 + w * 1024);            // B k1
    GLD16(gB + (size_t)64 * ldb + 32, dst + 28672 + w * 1024);
  };

  f32x4 acc[4][4];
  const f32x4 z = {0.f, 0.f, 0.f, 0.f};
#pragma unroll
  for (int i = 0; i < 4; i++)
#pragma unroll
    for (int j = 0; j < 4; j++) acc[i][j] = z;

  const int nt = K >> 6;
  STAGE(smem, 0);
  for (int t8 = 0; t8 < nt; t8++) {
    char* cur = smem + (t8 & 1) * 32768;
    char* nxt = smem + ((t8 & 1) ^ 1) * 32768;
    if (t8 < nt - 1) {
      STAGE(nxt, (t8 + 1) * 64);
      WAIT_VM8();
    } else {
      WAIT_VM0();
    }
    BARRIER();
#pragma unroll
    for (int kk = 0; kk < 2; kk++) {
      bf16x8 af[4], bfv[4];
#pragma unroll
      for (int i = 0; i < 4; i++)
        af[i] = *(const bf16x8*)(cur + kk * 8192 +
                                 (wr * 64 + i * 16 + lr) * 64 + ((lk * 2) ^ rsw));
#pragma unroll
      for (int j = 0; j < 4; j++)
        bfv[j] = *(const bf16x8*)(cur + 16384 + kk * 8192 +
                                  (wc * 64 + j * 16 + lr) * 64 + ((lk * 2) ^ rsw));
#pragma unroll
      for (int i = 0; i < 4; i++)
#pragma unroll
        for (int j = 0; j < 4; j++)
          acc[i][j] = __builtin_amdgcn_mfma_f32_16x16x32_bf16(af[i], bfv[j], acc[i][j], 0, 0, 0);
    }
    BARRIER();
  }

  if constexpr (EPI == EPI_XRT) {
    // t[c][m] = x[c][m] - acc/(1e-9+denom[m]); transpose in LDS -> tT[m][c] (bf16)
    float dinv[4];
#pragma unroll
    for (int j = 0; j < 4; j++)
      dinv[j] = 1.0f / (1e-9f + ep.scale[(size_t)b * ep.scale_stride +
                                         n0 + wc * 64 + j * 16 + lr]);
    const float* X = ep.xf + (size_t)b * ep.xf_stride;
#pragma unroll
    for (int i = 0; i < 4; i++) {
#pragma unroll
      for (int j = 0; j < 4; j++) {
#pragma unroll
        for (int r2 = 0; r2 < 4; r2 += 2) {
          int cl = wr * 64 + i * 16 + ((lane >> 4) << 2) + r2;
          int ml = wc * 64 + j * 16 + lr;
          float x0 = X[(size_t)(m0 + cl) * KN_ + n0 + ml];
          float x1 = X[(size_t)(m0 + cl + 1) * KN_ + n0 + ml];
          float t0 = x0 - acc[i][j][r2] * dinv[j];
          float t1 = x1 - acc[i][j][r2 + 1] * dinv[j];
          unsigned pk = (unsigned)f2bf(t0) | ((unsigned)f2bf(t1) << 16);
          int a = ((ml << 8) + (cl << 1)) ^ ((ml & 15) << 4);
          *(unsigned*)(smem + a) = pk;
        }
      }
    }
    __syncthreads();
    unsigned short* tT = (unsigned short*)Cv;
#pragma unroll
    for (int it = 0; it < 8; it++) {
      int ml = (t >> 4) + it * 16, chunk = t & 15;
      int a = ((ml << 8) + (chunk << 4)) ^ ((ml & 15) << 4);
      size_t g = ((size_t)b * KN_ + (n0 + ml)) * KC2_ + m0 + chunk * 8;
      *(bf16x8*)&tT[g] = *(const bf16x8*)(smem + a);
    }
    return;
  }

#pragma unroll
  for (int i = 0; i < 4; i++) {
#pragma unroll
    for (int r = 0; r < 4; r++) {
      const int row = m0 + wr * 64 + i * 16 + ((lane >> 4) << 2) + r;
      float pbias = 0.f, pinv = 1.f, padd = 0.f;
      if constexpr (EPI == EPI_BIAS) pbias = ep.bias[row];
      if constexpr (EPI == EPI_FINAL) {
        pbias = ep.bias[row];
        float iv = ep.gamma[row] * rsqrtf(ep.var[row] + 1e-5f);
        pinv = iv;
        padd = ep.beta[row] - ep.mean[row] * iv;
      }
#pragma unroll
      for (int j = 0; j < 4; j++) {
        const int col = n0 + wc * 64 + j * 16 + lr;
        float v = acc[i][j][r];
        size_t o = (size_t)b * sC + (size_t)row * ldc + col;
        if constexpr (EPI == EPI_PAIR) {
          unsigned short h = f2bf(v);
          ((unsigned short*)Cv)[o] = h;
          ((unsigned short*)Cv2)[o] = f2bf(v - bf2f(h));
        } else if constexpr (EPI == EPI_BIAS) {
          ((unsigned short*)Cv)[o] = f2bf(v + pbias);
        } else {  // EPI_FINAL
          float h = (v + pbias) * pinv + padd;
          h = fmaxf(h, 0.f);
          float xval = ep.xf[(size_t)b * ep.xf_stride + o - (size_t)b * sC];
          ((float*)Cv)[o] = h + xval;
        }
      }
    }
  }
}

// generic single-GEMM kernel (64 KB LDS, 2-phase)
template<int EPI>
__global__ __launch_bounds__(256) void gemm_one(
    const unsigned short* __restrict__ A0, const unsigned short* __restrict__ A1,
    long sA, int lda, int seg,
    const unsigned short* __restrict__ B0, const unsigned short* __restrict__ B1,
    long sB, int ldb,
    void* __restrict__ Cv, void* __restrict__ Cv2, long sC, int ldc, int K,
    EpiParams ep) {
  __shared__ __align__(16) char smem[65536];
  int bx, by, b;
  xcd_swizzle(bx, by, b);
  gemm_core<EPI>(smem, bx, by, b, A0, A1, sA, lda, seg, B0, B1, sB, ldb,
                 Cv, Cv2, sC, ldc, K, ep);
}

// fused x_q + x_k projections + raw x_v: one 768-block launch
__global__ __launch_bounds__(256) void proj3_kernel(
    const unsigned short* __restrict__ qThi, const unsigned short* __restrict__ qTlo,
    const unsigned short* __restrict__ Wqhi, const unsigned short* __restrict__ Wqlo,
    unsigned short* __restrict__ xqhi, unsigned short* __restrict__ xqlo,
    const unsigned short* __restrict__ xThi, const unsigned short* __restrict__ xTlo,
    const unsigned short* __restrict__ Wkhi, const unsigned short* __restrict__ Wklo,
    unsigned short* __restrict__ xkhi, unsigned short* __restrict__ xklo,
    const unsigned short* __restrict__ Wvb, unsigned short* __restrict__ x_v,
    const float* __restrict__ bv) {
  __shared__ __align__(16) char smem[65536];
  int f = (int)blockIdx.x;
  f = (f & 7) * 96 + (f >> 3);  // bijective XCD swizzle over 768
  EpiParams ep{};
  if (f < 256) {
    int bx = f & 1, by = (f >> 1) & 15, b = f >> 5;
    gemm_core<EPI_PAIR>(smem, bx, by, b, qThi, qTlo, (long)KN_ * KC_, KC_, KC_,
                        Wqhi, Wqlo, 0, KC_, xqhi, xqlo, (long)KN_ * KC2_, KC2_,
                        3 * KC_, ep);
  } else if (f < 512) {
    int g = f - 256;
    int bx = g & 1, by = (g >> 1) & 15, b = g >> 5;
    gemm_core<EPI_PAIR>(smem, bx, by, b, xThi, xTlo, (long)KN_ * KC2_, KC2_, KC2_,
                        Wkhi, Wklo, 0, KC2_, xkhi, xklo, (long)KN_ * KC2_, KC2_,
                        3 * KC2_, ep);
  } else {
    int g = f - 512;
    int bx = g & 15, by = (g >> 4) & 1, b = g >> 5;
    ep.bias = bv;
    gemm_core<EPI_BIAS>(smem, bx, by, b, Wvb, nullptr, 0, KC_, 0,
                        qThi, nullptr, (long)KN_ * KC_, KC_,
                        x_v, nullptr, (long)KC2_ * KN_, KN_, KC_, ep);
  }
}

// ---------------- launcher ----------------
extern "C" void kernel_launch(void* const* d_in, const int* in_sizes, int n_in,
                              void* d_out, int out_size, void* d_ws, size_t ws_size,
                              hipStream_t stream) {
  (void)in_sizes; (void)n_in; (void)out_size; (void)ws_size;
  const float* q     = (const float*)d_in[0];
  const float* x     = (const float*)d_in[1];
  const float* Wq    = (const float*)d_in[2];
  const float* Wk    = (const float*)d_in[3];
  const float* Wv    = (const float*)d_in[4];
  const float* bv    = (const float*)d_in[5];
  const float* Wt    = (const float*)d_in[6];
  const float* bt    = (const float*)d_in[7];
  const float* gamma = (const float*)d_in[8];
  const float* beta  = (const float*)d_in[9];
  const float* rmean = (const float*)d_in[10];
  const float* rvar  = (const float*)d_in[11];
  float* out = (float*)d_out;

  // workspace (~164 MiB)
  const size_t SZ_qT = (size_t)KB_ * KN_ * KC_ * 2;   // 16 MiB
  const size_t SZ_xT = (size_t)KB_ * KN_ * KC2_ * 2;  //  8 MiB
  char* ws = (char*)d_ws;
  size_t off = 0;
  auto alloc = [&](size_t bytes) {
    char* p = ws + off;
    off += (bytes + 255) & ~(size_t)255;
    return p;
  };
  unsigned short* qThi = (unsigned short*)alloc(SZ_qT);
  unsigned short* qTlo = (unsigned short*)alloc(SZ_qT);
  unsigned short* xThi = (unsigned short*)alloc(SZ_xT);
  unsigned short* xTlo = (unsigned short*)alloc(SZ_xT);
  unsigned short* xqhi = (unsigned short*)alloc(SZ_xT);
  unsigned short* xqlo = (unsigned short*)alloc(SZ_xT);
  unsigned short* xkhi = (unsigned short*)alloc(SZ_xT);
  unsigned short* xklo = (unsigned short*)alloc(SZ_xT);
  unsigned short* x_v  = (unsigned short*)alloc((size_t)KB_ * KC2_ * KN_ * 2);
  unsigned short* tT   = (unsigned short*)alloc(SZ_xT);
  unsigned short* Wqhi = (unsigned short*)alloc((size_t)KC2_ * KC_ * 2);
  unsigned short* Wqlo = (unsigned short*)alloc((size_t)KC2_ * KC_ * 2);
  unsigned short* Wkhi = (unsigned short*)alloc((size_t)KC2_ * KC2_ * 2);
  unsigned short* Wklo = (unsigned short*)alloc((size_t)KC2_ * KC2_ * 2);
  unsigned short* Wvb  = (unsigned short*)alloc((size_t)KC2_ * KC_ * 2);
  unsigned short* Wtb  = (unsigned short*)alloc((size_t)KC2_ * KC2_ * 2);
  float* rsv     = (float*)alloc((size_t)KB_ * KN_ * 4);
  float* denom   = (float*)alloc((size_t)KB_ * KN_ * 4);
  float* rowpart = (float*)alloc((size_t)KB_ * KN_ * 32 * 4);
  unsigned short* uT = (unsigned short*)alloc((size_t)KB_ * KN_ * KN_ * 2);   // 64 MiB

  dim3 blk(256);

  // weights -> bf16
  cvt_pair_kernel<<<dim3(KC2_ * KC_ / 1024), blk, 0, stream>>>(Wq, Wqhi, Wqlo, KC2_ * KC_);
  cvt_pair_kernel<<<dim3(KC2_ * KC2_ / 1024), blk, 0, stream>>>(Wk, Wkhi, Wklo, KC2_ * KC2_);
  cvt_kernel<<<dim3(KC2_ * KC_ / 1024), blk, 0, stream>>>(Wv, Wvb, KC2_ * KC_);
  cvt_kernel<<<dim3(KC2_ * KC2_ / 1024), blk, 0, stream>>>(Wt, Wtb, KC2_ * KC2_);

  // q^T, x^T fp32 -> hi/lo bf16 pairs (K contiguous)
  transpose_pair_kernel<<<dim3(KN_ / 64, KC_ / 64, KB_), blk, 0, stream>>>(
      q, (long)KC_ * KN_, qThi, qTlo, (long)KN_ * KC_, KC_, KN_);
  transpose_pair_kernel<<<dim3(KN_ / 64, KC2_ / 64, KB_), blk, 0, stream>>>(
      x, (long)KC2_ * KN_, xThi, xTlo, (long)KN_ * KC2_, KC2_, KN_);

  // x_q / x_kT projections (fp32-grade via segmented-K) + raw x_v
  proj3_kernel<<<dim3(768), blk, 0, stream>>>(qThi, qTlo, Wqhi, Wqlo, xqhi, xqlo,
                                              xThi, xTlo, Wkhi, Wklo, xkhi, xklo,
                                              Wvb, x_v, bv);

  // energy + exp + transpose + row partials (256x256 tile, 8 waves)
  energy_kernel<<<dim3(KN_ / 256, KN_ / 256, KB_), dim3(512), 0, stream>>>(
      xqhi, xqlo, xkhi, xklo, uT, rowpart);
  rowreduce_kernel<<<dim3(KB_ * KN_ / 256), blk, 0, stream>>>(rowpart, rsv);

  // x_v *= rsv (in-place)
  xvscale_kernel<<<dim3(KB_ * KC2_ * KN_ / 8 / 256), blk, 0, stream>>>(x_v, rsv);

  // denom[b][m] = sum_n uT[m][n] * rsv[n]
  denom_kernel<<<dim3(KN_ / 4, KB_), blk, 0, stream>>>(uT, rsv, denom);

  // x_r GEMM with fused renorm + subtract + transpose -> tT[m][c]
  EpiParams e5{}; e5.xf = x; e5.xf_stride = (long)KC2_ * KN_;
  e5.scale = denom; e5.scale_stride = KN_;
  gemm_one<EPI_XRT><<<dim3(KN_ / 128, KC2_ / 128, KB_), blk, 0, stream>>>(
      x_v, nullptr, (long)KC2_ * KN_, KN_, 0, uT, nullptr, (long)KN_ * KN_, KN_,
      tT, nullptr, 0, 0, KN_, e5);

  // out[b][o][n] = relu(BN(Wt[o][:].tT[n][:] + bt[o])) + x[b][o][n]
  EpiParams e6{}; e6.bias = bt; e6.xf = x; e6.xf_stride = (long)KC2_ * KN_;
  e6.gamma = gamma; e6.beta = beta; e6.mean = rmean; e6.var = rvar;
  gemm_one<EPI_FINAL><<<dim3(KN_ / 128, KC2_ / 128, KB_), blk, 0, stream>>>(
      Wtb, nullptr, 0, KC2_, 0, tT, nullptr, (long)KN_ * KC2_, KC2_,
      out, nullptr, (long)KC2_ * KN_, KN_, KC2_, e6);
}

// Round 11
// 191.322 us; speedup vs baseline: 1.1056x; 1.1056x over previous
//
#include <hip/hip_runtime.h>
#include <cstdint>
#include <cstddef>

// Problem constants (B, C, N fixed by the reference)
#define KB_  8
#define KC_  512
#define KC2_ 256
#define KN_  2048

typedef __attribute__((ext_vector_type(8))) __bf16 bf16x8;
typedef __attribute__((ext_vector_type(8))) unsigned short u16x8;
typedef __attribute__((ext_vector_type(4))) float f32x4;

__device__ __forceinline__ unsigned short f2bf(float f) {
  union { float f; unsigned u; } x; x.f = f;
  unsigned r = x.u + 0x7fffu + ((x.u >> 16) & 1u);  // RNE (finite values only)
  return (unsigned short)(r >> 16);
}
__device__ __forceinline__ float bf2f(unsigned short h) {
  union { unsigned u; float f; } x; x.u = ((unsigned)h) << 16;
  return x.f;
}

// async global->LDS, 16B per lane; LDS dest = wave-uniform base + lane*16 (linear!)
#define GLD16(g, l) __builtin_amdgcn_global_load_lds( \
    (__attribute__((address_space(1))) void*)(g),     \
    (__attribute__((address_space(3))) void*)(l), 16, 0, 0)

// counted-vmcnt barrier pair (T4): wait only the CURRENT buffer's 8 loads;
// next-tile loads stay in flight across the barrier.
#define WAIT_VM8()  asm volatile("s_waitcnt vmcnt(8)" ::: "memory")
#define WAIT_VM0()  asm volatile("s_waitcnt vmcnt(0)" ::: "memory")
#define BARRIER()   __builtin_amdgcn_s_barrier()

// bijective XCD-aware block swizzle (nb % 8 == 0 for all our grids)
__device__ __forceinline__ void xcd_swizzle(int& bx, int& by, int& bz) {
  const int gx = gridDim.x, gy = gridDim.y;
  const int nb = gx * gy * (int)gridDim.z;
  int f = ((int)blockIdx.z * gy + (int)blockIdx.y) * gx + (int)blockIdx.x;
  if ((nb & 7) == 0) f = (f & 7) * (nb >> 3) + (f >> 3);
  const int gxy = gx * gy;
  bz = f / gxy; int rem = f - bz * gxy;
  by = rem / gx; bx = rem - by * gx;
}

// ---------------- all weight conversions in one launch (384 blocks) ----------------
__global__ __launch_bounds__(256) void cvt_all_kernel(
    const float* __restrict__ Wq, const float* __restrict__ Wk,
    const float* __restrict__ Wv, const float* __restrict__ Wt,
    unsigned short* __restrict__ Wqhi, unsigned short* __restrict__ Wqlo,
    unsigned short* __restrict__ Wkhi, unsigned short* __restrict__ Wklo,
    unsigned short* __restrict__ Wvb, unsigned short* __restrict__ Wtb) {
  int blk = blockIdx.x, t = threadIdx.x;
  if (blk < 128) {                     // Wq -> hi/lo pair (131072 elems)
    int i = (blk * 256 + t) * 4;
    float4 f = *(const float4*)(Wq + i);
    ushort4 h = { f2bf(f.x), f2bf(f.y), f2bf(f.z), f2bf(f.w) };
    ushort4 l = { f2bf(f.x - bf2f(h.x)), f2bf(f.y - bf2f(h.y)),
                  f2bf(f.z - bf2f(h.z)), f2bf(f.w - bf2f(h.w)) };
    *(ushort4*)(Wqhi + i) = h; *(ushort4*)(Wqlo + i) = l;
  } else if (blk < 192) {              // Wk -> hi/lo pair (65536)
    int i = ((blk - 128) * 256 + t) * 4;
    float4 f = *(const float4*)(Wk + i);
    ushort4 h = { f2bf(f.x), f2bf(f.y), f2bf(f.z), f2bf(f.w) };
    ushort4 l = { f2bf(f.x - bf2f(h.x)), f2bf(f.y - bf2f(h.y)),
                  f2bf(f.z - bf2f(h.z)), f2bf(f.w - bf2f(h.w)) };
    *(ushort4*)(Wkhi + i) = h; *(ushort4*)(Wklo + i) = l;
  } else if (blk < 320) {              // Wv -> single bf16 (131072)
    int i = ((blk - 192) * 256 + t) * 4;
    float4 f = *(const float4*)(Wv + i);
    ushort4 u = { f2bf(f.x), f2bf(f.y), f2bf(f.z), f2bf(f.w) };
    *(ushort4*)(Wvb + i) = u;
  } else {                             // Wt -> single bf16 (65536)
    int i = ((blk - 320) * 256 + t) * 4;
    float4 f = *(const float4*)(Wt + i);
    ushort4 u = { f2bf(f.x), f2bf(f.y), f2bf(f.z), f2bf(f.w) };
    *(ushort4*)(Wtb + i) = u;
  }
}

// ---------------- merged q/x transpose: fp32 [R][N] -> bf16 hi/lo [N][R] ----------------
// grid (KN/64, 12, KB): by<8 -> q (R=512), else x (R=256)
__global__ __launch_bounds__(256) void transpose2_kernel(
    const float* __restrict__ q, const float* __restrict__ x,
    unsigned short* __restrict__ qThi, unsigned short* __restrict__ qTlo,
    unsigned short* __restrict__ xThi, unsigned short* __restrict__ xTlo) {
  int b = blockIdx.z;
  const float* in; unsigned short *hi, *lo; int R, r0;
  if (blockIdx.y < 8) {
    in = q + (size_t)b * KC_ * KN_;  hi = qThi; lo = qTlo;
    R = KC_;  r0 = blockIdx.y * 64;
    hi += (size_t)b * KN_ * KC_;  lo += (size_t)b * KN_ * KC_;
  } else {
    in = x + (size_t)b * KC2_ * KN_; hi = xThi; lo = xTlo;
    R = KC2_; r0 = (blockIdx.y - 8) * 64;
    hi += (size_t)b * KN_ * KC2_; lo += (size_t)b * KN_ * KC2_;
  }
  __shared__ float tile[64][65];
  int t = threadIdx.x;
  int c0 = blockIdx.x * 64;
#pragma unroll
  for (int k = 0; k < 4; k++) {
    int vi = k * 256 + t, rr = vi >> 4, cv = vi & 15;
    float4 f = *(const float4*)&in[(size_t)(r0 + rr) * KN_ + c0 + cv * 4];
    tile[rr][cv * 4 + 0] = f.x; tile[rr][cv * 4 + 1] = f.y;
    tile[rr][cv * 4 + 2] = f.z; tile[rr][cv * 4 + 3] = f.w;
  }
  __syncthreads();
#pragma unroll
  for (int k = 0; k < 4; k++) {
    int vi = k * 256 + t, cc = vi >> 4, rv = vi & 15;
    float f0 = tile[rv * 4 + 0][cc], f1 = tile[rv * 4 + 1][cc];
    float f2 = tile[rv * 4 + 2][cc], f3 = tile[rv * 4 + 3][cc];
    ushort4 h = { f2bf(f0), f2bf(f1), f2bf(f2), f2bf(f3) };
    ushort4 l = { f2bf(f0 - bf2f(h.x)), f2bf(f1 - bf2f(h.y)),
                  f2bf(f2 - bf2f(h.z)), f2bf(f3 - bf2f(h.w)) };
    size_t o = (size_t)(c0 + cc) * R + r0 + rv * 4;
    *(ushort4*)&hi[o] = h;
    *(ushort4*)&lo[o] = l;
  }
}

// ---------------- rsv[b][n] = 1 / sum_k rowpart[b][n][k] ----------------
__global__ __launch_bounds__(256) void rowreduce_kernel(const float* __restrict__ rowpart,
                                                        float* __restrict__ rsv) {
  int idx = blockIdx.x * 256 + threadIdx.x;  // 8*2048 rows
  const float* p = rowpart + (size_t)idx * 32;
  float s = 0.f;
#pragma unroll
  for (int k = 0; k < 32; k++) s += p[k];
  rsv[idx] = 1.0f / s;
}

// ---------------- denom[b][m] = sum_n uT[b][m][n] * rsv[b][n] ----------------
__global__ __launch_bounds__(256) void denom_kernel(const unsigned short* __restrict__ uT,
                                                    const float* __restrict__ rsv,
                                                    float* __restrict__ denom) {
  int b = blockIdx.y;
  int m = blockIdx.x * 4 + (threadIdx.x >> 6);
  int lane = threadIdx.x & 63;
  const unsigned short* U = uT + ((size_t)b * KN_ + m) * KN_;
  const float* R = rsv + (size_t)b * KN_;
  float s = 0.f;
#pragma unroll
  for (int c = 0; c < 4; c++) {
    int n = c * 512 + lane * 8;
    u16x8 u = *(const u16x8*)&U[n];
    float4 r0 = *(const float4*)&R[n];
    float4 r1 = *(const float4*)&R[n + 4];
    s += bf2f(u[0]) * r0.x + bf2f(u[1]) * r0.y + bf2f(u[2]) * r0.z + bf2f(u[3]) * r0.w;
    s += bf2f(u[4]) * r1.x + bf2f(u[5]) * r1.y + bf2f(u[6]) * r1.z + bf2f(u[7]) * r1.w;
  }
#pragma unroll
  for (int o = 32; o > 0; o >>= 1) s += __shfl_xor(s, o, 64);
  if (lane == 0) denom[(size_t)b * KN_ + m] = s;
}

// ---------------- energy kernel: 128x128, 4 waves, 2-phase dbuf (counted vmcnt)
//                   split hi/lo GEMM + exp + transpose + row-partials ----
__global__ __launch_bounds__(256) void energy_kernel(
    const unsigned short* __restrict__ Ahi, const unsigned short* __restrict__ Alo,
    const unsigned short* __restrict__ Bhi, const unsigned short* __restrict__ Blo,
    unsigned short* __restrict__ uT, float* __restrict__ rowpart) {
  int bx, by, b;
  xcd_swizzle(bx, by, b);  // grid (16,16,8): each XCD owns one batch
  Ahi += (size_t)b * KN_ * KC2_; Alo += (size_t)b * KN_ * KC2_;
  Bhi += (size_t)b * KN_ * KC2_; Blo += (size_t)b * KN_ * KC2_;
  const int m0 = by * 128;  // rows = n (query idx)
  const int n0 = bx * 128;  // cols = m (key idx)
  __shared__ __align__(16) char smem[65536];  // 2 phases x 32KB; phase0 reused for transpose
  const int t = threadIdx.x, lane = t & 63, w = t >> 6;
  const int wr = w >> 1, wc = w & 1;
  const int srow = t >> 2;
  const int scol = (((t & 3) ^ ((srow >> 1) & 3)) * 8);   // pre-swizzled k-chunk
  const int lr = lane & 15, lk = (lane >> 4) * 8;
  const int rsw = ((lr >> 1) & 3) << 4;                   // read-side XOR (bytes)

  auto STAGE = [&](char* dst, int kt) {
    const size_t ga = (size_t)(m0 + srow) * KC2_ + kt + scol;
    const size_t gb = (size_t)(n0 + srow) * KC2_ + kt + scol;
    GLD16(Ahi + ga, dst + 0 + w * 1024);
    GLD16(Ahi + ga + (size_t)64 * KC2_, dst + 4096 + w * 1024);
    GLD16(Alo + ga, dst + 8192 + w * 1024);
    GLD16(Alo + ga + (size_t)64 * KC2_, dst + 12288 + w * 1024);
    GLD16(Bhi + gb, dst + 16384 + w * 1024);
    GLD16(Bhi + gb + (size_t)64 * KC2_, dst + 20480 + w * 1024);
    GLD16(Blo + gb, dst + 24576 + w * 1024);
    GLD16(Blo + gb + (size_t)64 * KC2_, dst + 28672 + w * 1024);
  };

  f32x4 acc[4][4];
  const f32x4 z = {0.f, 0.f, 0.f, 0.f};
#pragma unroll
  for (int i = 0; i < 4; i++)
#pragma unroll
    for (int j = 0; j < 4; j++) acc[i][j] = z;

  STAGE(smem, 0);
  for (int kt8 = 0; kt8 < 8; kt8++) {
    char* cur = smem + (kt8 & 1) * 32768;
    char* nxt = smem + ((kt8 & 1) ^ 1) * 32768;
    if (kt8 < 7) {
      STAGE(nxt, (kt8 + 1) * 32);  // +8 loads in flight
      WAIT_VM8();                  // wait only cur's 8 (oldest)
    } else {
      WAIT_VM0();
    }
    BARRIER();                     // all waves' cur-loads visible
    bf16x8 ah[4], al[4], bh[4], bl[4];
#pragma unroll
    for (int i = 0; i < 4; i++) {
      int ro = (wr * 64 + i * 16 + lr) * 64 + ((lk * 2) ^ rsw);
      ah[i] = *(const bf16x8*)(cur + 0 + ro);
      al[i] = *(const bf16x8*)(cur + 8192 + ro);
    }
#pragma unroll
    for (int j = 0; j < 4; j++) {
      int ro = (wc * 64 + j * 16 + lr) * 64 + ((lk * 2) ^ rsw);
      bh[j] = *(const bf16x8*)(cur + 16384 + ro);
      bl[j] = *(const bf16x8*)(cur + 24576 + ro);
    }
    __builtin_amdgcn_s_setprio(1);  // T5: favor MFMA-issuing wave over staging waves
#pragma unroll
    for (int i = 0; i < 4; i++)
#pragma unroll
      for (int j = 0; j < 4; j++) {
        acc[i][j] = __builtin_amdgcn_mfma_f32_16x16x32_bf16(al[i], bh[j], acc[i][j], 0, 0, 0);
        acc[i][j] = __builtin_amdgcn_mfma_f32_16x16x32_bf16(ah[i], bl[j], acc[i][j], 0, 0, 0);
        acc[i][j] = __builtin_amdgcn_mfma_f32_16x16x32_bf16(ah[i], bh[j], acc[i][j], 0, 0, 0);
      }
    __builtin_amdgcn_s_setprio(0);
    BARRIER();                     // all reads of cur done before it's restaged
  }

  // ---- u = exp(E - 40) ----
#pragma unroll
  for (int i = 0; i < 4; i++)
#pragma unroll
    for (int j = 0; j < 4; j++)
#pragma unroll
      for (int r = 0; r < 4; r++) acc[i][j][r] = __expf(acc[i][j][r] - 40.f);

  // ---- partial row sums ----
#pragma unroll
  for (int i = 0; i < 4; i++) {
#pragma unroll
    for (int r = 0; r < 4; r++) {
      float s = acc[i][0][r] + acc[i][1][r] + acc[i][2][r] + acc[i][3][r];
      s += __shfl_xor(s, 1, 64); s += __shfl_xor(s, 2, 64);
      s += __shfl_xor(s, 4, 64); s += __shfl_xor(s, 8, 64);
      if ((lane & 15) == 0) {
        int row = m0 + wr * 64 + i * 16 + ((lane >> 4) << 2) + r;
        rowpart[((size_t)b * KN_ + row) * 32 + bx * 2 + wc] = s;
      }
    }
  }

  // ---- transpose to uT via LDS (XOR-swizzled banks) ----
#pragma unroll
  for (int i = 0; i < 4; i++) {
#pragma unroll
    for (int j = 0; j < 4; j++) {
#pragma unroll
      for (int r2 = 0; r2 < 4; r2 += 2) {
        int qn = wr * 64 + i * 16 + ((lane >> 4) << 2) + r2;
        int km = wc * 64 + j * 16 + lr;
        unsigned pk = (unsigned)f2bf(acc[i][j][r2]) |
                      ((unsigned)f2bf(acc[i][j][r2 + 1]) << 16);
        int a = ((km << 8) + (qn << 1)) ^ ((km & 15) << 4);
        *(unsigned*)(smem + a) = pk;
      }
    }
  }
  __syncthreads();
  // read 16B per lane, 16 lanes cooperate per uT row -> 256B coalesced bursts
#pragma unroll
  for (int it = 0; it < 8; it++) {
    int km = (t >> 4) + it * 16, chunk = t & 15;
    int a = ((km << 8) + (chunk << 4)) ^ ((km & 15) << 4);
    size_t g = ((size_t)b * KN_ + (n0 + km)) * KN_ + m0 + chunk * 8;
    *(bf16x8*)&uT[g] = *(const bf16x8*)(smem + a);
  }
}

// ---------------- epilogue variants ----------------
enum { EPI_PAIR = 0, EPI_VSCALE = 2, EPI_XRT = 3, EPI_FINAL = 4 };

struct EpiParams {
  const float* bias;
  const float* xf;  long xf_stride;
  const float* scale; long scale_stride;
  const float* gamma; const float* beta; const float* mean; const float* var;
};

// ============== unified MFMA GEMM core, 128x128 tile, BK=64, 2-phase dbuf
// with counted vmcnt; segmented-K: if seg>0 (K=3*seg): A'=[A0|A1|A0], B'=[B0|B0|B1]. ====
template<int EPI>
__device__ __forceinline__ void gemm_core(
    char* __restrict__ smem, int bx, int by, int b,
    const unsigned short* __restrict__ A0, const unsigned short* __restrict__ A1,
    long sA, int lda, int seg,
    const unsigned short* __restrict__ B0, const unsigned short* __restrict__ B1,
    long sB, int ldb,
    void* __restrict__ Cv, void* __restrict__ Cv2, long sC, int ldc, int K,
    const EpiParams& ep) {
  A0 += (size_t)b * sA; A1 += (size_t)b * sA;
  B0 += (size_t)b * sB; B1 += (size_t)b * sB;
  const int m0 = by * 128, n0 = bx * 128;
  const int t = threadIdx.x, lane = t & 63, w = t >> 6;
  const int wr = w >> 1, wc = w & 1;
  const int srow = t >> 2;
  const int scol = (((t & 3) ^ ((srow >> 1) & 3)) * 8);   // pre-swizzled k-chunk
  const int lr = lane & 15, lk = (lane >> 4) * 8;
  const int rsw = ((lr >> 1) & 3) << 4;                   // read-side XOR (bytes)

  auto STAGE = [&](char* dst, int kt) {
    int s = seg ? ((kt >= seg) + (kt >= 2 * seg)) : 0;
    int kl = kt - s * seg;
    const unsigned short* Ab = (s == 1) ? A1 : A0;
    const unsigned short* Bb = (s == 2) ? B1 : B0;
    const unsigned short* gA = Ab + (size_t)(m0 + srow) * lda + kl + scol;
    const unsigned short* gB = Bb + (size_t)(n0 + srow) * ldb + kl + scol;
    GLD16(gA, dst + w * 1024);                         // A k0
    GLD16(gA + (size_t)64 * lda, dst + 4096 + w * 1024);
    GLD16(gA + 32, dst + 8192 + w * 1024);             // A k1
    GLD16(gA + (size_t)64 * lda + 32, dst + 12288 + w * 1024);
    GLD16(gB, dst + 16384 + w * 1024);                 // B k0
    GLD16(gB + (size_t)64 * ldb, dst + 20480 + w * 1024);
    GLD16(gB + 32, dst + 24576 + w * 1024);            // B k1
    GLD16(gB + (size_t)64 * ldb + 32, dst + 28672 + w * 1024);
  };

  f32x4 acc[4][4];
  const f32x4 z = {0.f, 0.f, 0.f, 0.f};
#pragma unroll
  for (int i = 0; i < 4; i++)
#pragma unroll
    for (int j = 0; j < 4; j++) acc[i][j] = z;

  const int nt = K >> 6;
  STAGE(smem, 0);
  for (int t8 = 0; t8 < nt; t8++) {
    char* cur = smem + (t8 & 1) * 32768;
    char* nxt = smem + ((t8 & 1) ^ 1) * 32768;
    if (t8 < nt - 1) {
      STAGE(nxt, (t8 + 1) * 64);
      WAIT_VM8();
    } else {
      WAIT_VM0();
    }
    BARRIER();
#pragma unroll
    for (int kk = 0; kk < 2; kk++) {
      bf16x8 af[4], bfv[4];
#pragma unroll
      for (int i = 0; i < 4; i++)
        af[i] = *(const bf16x8*)(cur + kk * 8192 +
                                 (wr * 64 + i * 16 + lr) * 64 + ((lk * 2) ^ rsw));
#pragma unroll
      for (int j = 0; j < 4; j++)
        bfv[j] = *(const bf16x8*)(cur + 16384 + kk * 8192 +
                                  (wc * 64 + j * 16 + lr) * 64 + ((lk * 2) ^ rsw));
#pragma unroll
      for (int i = 0; i < 4; i++)
#pragma unroll
        for (int j = 0; j < 4; j++)
          acc[i][j] = __builtin_amdgcn_mfma_f32_16x16x32_bf16(af[i], bfv[j], acc[i][j], 0, 0, 0);
    }
    BARRIER();
  }

  if constexpr (EPI == EPI_XRT) {
    // t[c][m] = x[c][m] - acc/(1e-9+denom[m]); transpose in LDS -> tT[m][c] (bf16)
    float dinv[4];
#pragma unroll
    for (int j = 0; j < 4; j++)
      dinv[j] = 1.0f / (1e-9f + ep.scale[(size_t)b * ep.scale_stride +
                                         n0 + wc * 64 + j * 16 + lr]);
    const float* X = ep.xf + (size_t)b * ep.xf_stride;
#pragma unroll
    for (int i = 0; i < 4; i++) {
#pragma unroll
      for (int j = 0; j < 4; j++) {
#pragma unroll
        for (int r2 = 0; r2 < 4; r2 += 2) {
          int cl = wr * 64 + i * 16 + ((lane >> 4) << 2) + r2;
          int ml = wc * 64 + j * 16 + lr;
          float x0 = X[(size_t)(m0 + cl) * KN_ + n0 + ml];
          float x1 = X[(size_t)(m0 + cl + 1) * KN_ + n0 + ml];
          float t0 = x0 - acc[i][j][r2] * dinv[j];
          float t1 = x1 - acc[i][j][r2 + 1] * dinv[j];
          unsigned pk = (unsigned)f2bf(t0) | ((unsigned)f2bf(t1) << 16);
          int a = ((ml << 8) + (cl << 1)) ^ ((ml & 15) << 4);
          *(unsigned*)(smem + a) = pk;
        }
      }
    }
    __syncthreads();
    unsigned short* tT = (unsigned short*)Cv;
#pragma unroll
    for (int it = 0; it < 8; it++) {
      int ml = (t >> 4) + it * 16, chunk = t & 15;
      int a = ((ml << 8) + (chunk << 4)) ^ ((ml & 15) << 4);
      size_t g = ((size_t)b * KN_ + (n0 + ml)) * KC2_ + m0 + chunk * 8;
      *(bf16x8*)&tT[g] = *(const bf16x8*)(smem + a);
    }
    return;
  }

#pragma unroll
  for (int i = 0; i < 4; i++) {
#pragma unroll
    for (int r = 0; r < 4; r++) {
      const int row = m0 + wr * 64 + i * 16 + ((lane >> 4) << 2) + r;
      float pbias = 0.f, pinv = 1.f, padd = 0.f;
      if constexpr (EPI == EPI_VSCALE) pbias = ep.bias[row];
      if constexpr (EPI == EPI_FINAL) {
        pbias = ep.bias[row];
        float iv = ep.gamma[row] * rsqrtf(ep.var[row] + 1e-5f);
        pinv = iv;
        padd = ep.beta[row] - ep.mean[row] * iv;
      }
#pragma unroll
      for (int j = 0; j < 4; j++) {
        const int col = n0 + wc * 64 + j * 16 + lr;
        float v = acc[i][j][r];
        size_t o = (size_t)b * sC + (size_t)row * ldc + col;
        if constexpr (EPI == EPI_PAIR) {
          unsigned short h = f2bf(v);
          ((unsigned short*)Cv)[o] = h;
          ((unsigned short*)Cv2)[o] = f2bf(v - bf2f(h));
        } else if constexpr (EPI == EPI_VSCALE) {
          float sc = ep.scale[(size_t)b * ep.scale_stride + col];
          ((unsigned short*)Cv)[o] = f2bf((v + pbias) * sc);
        } else {  // EPI_FINAL
          float h = (v + pbias) * pinv + padd;
          h = fmaxf(h, 0.f);
          float xval = ep.xf[(size_t)b * ep.xf_stride + o - (size_t)b * sC];
          ((float*)Cv)[o] = h + xval;
        }
      }
    }
  }
}

// generic single-GEMM kernel (64 KB LDS, 2-phase)
template<int EPI>
__global__ __launch_bounds__(256) void gemm_one(
    const unsigned short* __restrict__ A0, const unsigned short* __restrict__ A1,
    long sA, int lda, int seg,
    const unsigned short* __restrict__ B0, const unsigned short* __restrict__ B1,
    long sB, int ldb,
    void* __restrict__ Cv, void* __restrict__ Cv2, long sC, int ldc, int K,
    EpiParams ep) {
  __shared__ __align__(16) char smem[65536];
  int bx, by, b;
  xcd_swizzle(bx, by, b);
  gemm_core<EPI>(smem, bx, by, b, A0, A1, sA, lda, seg, B0, B1, sB, ldb,
                 Cv, Cv2, sC, ldc, K, ep);
}

// fused x_q + x_k projections: one 512-block launch
__global__ __launch_bounds__(256) void proj2_kernel(
    const unsigned short* __restrict__ qThi, const unsigned short* __restrict__ qTlo,
    const unsigned short* __restrict__ Wqhi, const unsigned short* __restrict__ Wqlo,
    unsigned short* __restrict__ xqhi, unsigned short* __restrict__ xqlo,
    const unsigned short* __restrict__ xThi, const unsigned short* __restrict__ xTlo,
    const unsigned short* __restrict__ Wkhi, const unsigned short* __restrict__ Wklo,
    unsigned short* __restrict__ xkhi, unsigned short* __restrict__ xklo) {
  __shared__ __align__(16) char smem[65536];
  int f = (int)blockIdx.x;
  f = (f & 7) * 64 + (f >> 3);  // XCD swizzle over 512
  EpiParams ep{};
  if (f < 256) {
    int bx = f & 1, by = (f >> 1) & 15, b = f >> 5;
    gemm_core<EPI_PAIR>(smem, bx, by, b, qThi, qTlo, (long)KN_ * KC_, KC_, KC_,
                        Wqhi, Wqlo, 0, KC_, xqhi, xqlo, (long)KN_ * KC2_, KC2_,
                        3 * KC_, ep);
  } else {
    int g = f - 256;
    int bx = g & 1, by = (g >> 1) & 15, b = g >> 5;
    gemm_core<EPI_PAIR>(smem, bx, by, b, xThi, xTlo, (long)KN_ * KC2_, KC2_, KC2_,
                        Wkhi, Wklo, 0, KC2_, xkhi, xklo, (long)KN_ * KC2_, KC2_,
                        3 * KC2_, ep);
  }
}

// ---------------- launcher ----------------
extern "C" void kernel_launch(void* const* d_in, const int* in_sizes, int n_in,
                              void* d_out, int out_size, void* d_ws, size_t ws_size,
                              hipStream_t stream) {
  (void)in_sizes; (void)n_in; (void)out_size; (void)ws_size;
  const float* q     = (const float*)d_in[0];
  const float* x     = (const float*)d_in[1];
  const float* Wq    = (const float*)d_in[2];
  const float* Wk    = (const float*)d_in[3];
  const float* Wv    = (const float*)d_in[4];
  const float* bv    = (const float*)d_in[5];
  const float* Wt    = (const float*)d_in[6];
  const float* bt    = (const float*)d_in[7];
  const float* gamma = (const float*)d_in[8];
  const float* beta  = (const float*)d_in[9];
  const float* rmean = (const float*)d_in[10];
  const float* rvar  = (const float*)d_in[11];
  float* out = (float*)d_out;

  // workspace (~164 MiB)
  const size_t SZ_qT = (size_t)KB_ * KN_ * KC_ * 2;   // 16 MiB
  const size_t SZ_xT = (size_t)KB_ * KN_ * KC2_ * 2;  //  8 MiB
  char* ws = (char*)d_ws;
  size_t off = 0;
  auto alloc = [&](size_t bytes) {
    char* p = ws + off;
    off += (bytes + 255) & ~(size_t)255;
    return p;
  };
  unsigned short* qThi = (unsigned short*)alloc(SZ_qT);
  unsigned short* qTlo = (unsigned short*)alloc(SZ_qT);
  unsigned short* xThi = (unsigned short*)alloc(SZ_xT);
  unsigned short* xTlo = (unsigned short*)alloc(SZ_xT);
  unsigned short* xqhi = (unsigned short*)alloc(SZ_xT);
  unsigned short* xqlo = (unsigned short*)alloc(SZ_xT);
  unsigned short* xkhi = (unsigned short*)alloc(SZ_xT);
  unsigned short* xklo = (unsigned short*)alloc(SZ_xT);
  unsigned short* x_v  = (unsigned short*)alloc((size_t)KB_ * KC2_ * KN_ * 2);
  unsigned short* tT   = (unsigned short*)alloc(SZ_xT);
  unsigned short* Wqhi = (unsigned short*)alloc((size_t)KC2_ * KC_ * 2);
  unsigned short* Wqlo = (unsigned short*)alloc((size_t)KC2_ * KC_ * 2);
  unsigned short* Wkhi = (unsigned short*)alloc((size_t)KC2_ * KC2_ * 2);
  unsigned short* Wklo = (unsigned short*)alloc((size_t)KC2_ * KC2_ * 2);
  unsigned short* Wvb  = (unsigned short*)alloc((size_t)KC2_ * KC_ * 2);
  unsigned short* Wtb  = (unsigned short*)alloc((size_t)KC2_ * KC2_ * 2);
  float* rsv     = (float*)alloc((size_t)KB_ * KN_ * 4);
  float* denom   = (float*)alloc((size_t)KB_ * KN_ * 4);
  float* rowpart = (float*)alloc((size_t)KB_ * KN_ * 32 * 4);
  unsigned short* uT = (unsigned short*)alloc((size_t)KB_ * KN_ * KN_ * 2);   // 64 MiB

  dim3 blk(256);

  // all weight conversions (one launch)
  cvt_all_kernel<<<dim3(384), blk, 0, stream>>>(Wq, Wk, Wv, Wt,
                                                Wqhi, Wqlo, Wkhi, Wklo, Wvb, Wtb);

  // q^T and x^T in one launch: fp32 -> hi/lo bf16 pairs (K contiguous)
  transpose2_kernel<<<dim3(KN_ / 64, 12, KB_), blk, 0, stream>>>(
      q, x, qThi, qTlo, xThi, xTlo);

  // x_q / x_kT projections (fp32-grade via segmented-K)
  proj2_kernel<<<dim3(512), blk, 0, stream>>>(qThi, qTlo, Wqhi, Wqlo, xqhi, xqlo,
                                              xThi, xTlo, Wkhi, Wklo, xkhi, xklo);

  // energy + exp + transpose + row partials (2-phase dbuf, counted vmcnt, setprio)
  energy_kernel<<<dim3(KN_ / 128, KN_ / 128, KB_), blk, 0, stream>>>(
      xqhi, xqlo, xkhi, xklo, uT, rowpart);
  rowreduce_kernel<<<dim3(KB_ * KN_ / 256), blk, 0, stream>>>(rowpart, rsv);

  // x_v'[b][o][n] = (Wv[o][:].qT[n][:] + bv[o]) * rsv[b][n]
  EpiParams e3{}; e3.bias = bv; e3.scale = rsv; e3.scale_stride = KN_;
  gemm_one<EPI_VSCALE><<<dim3(KN_ / 128, KC2_ / 128, KB_), blk, 0, stream>>>(
      Wvb, nullptr, 0, KC_, 0, qThi, nullptr, (long)KN_ * KC_, KC_,
      x_v, nullptr, (long)KC2_ * KN_, KN_, KC_, e3);

  // denom[b][m] = sum_n uT[m][n] * rsv[n]
  denom_kernel<<<dim3(KN_ / 4, KB_), blk, 0, stream>>>(uT, rsv, denom);

  // x_r GEMM with fused renorm + subtract + transpose -> tT[m][c]
  EpiParams e5{}; e5.xf = x; e5.xf_stride = (long)KC2_ * KN_;
  e5.scale = denom; e5.scale_stride = KN_;
  gemm_one<EPI_XRT><<<dim3(KN_ / 128, KC2_ / 128, KB_), blk, 0, stream>>>(
      x_v, nullptr, (long)KC2_ * KN_, KN_, 0, uT, nullptr, (long)KN_ * KN_, KN_,
      tT, nullptr, 0, 0, KN_, e5);

  // out[b][o][n] = relu(BN(Wt[o][:].tT[n][:] + bt[o])) + x[b][o][n]
  EpiParams e6{}; e6.bias = bt; e6.xf = x; e6.xf_stride = (long)KC2_ * KN_;
  e6.gamma = gamma; e6.beta = beta; e6.mean = rmean; e6.var = rvar;
  gemm_one<EPI_FINAL><<<dim3(KN_ / 128, KC2_ / 128, KB_), blk, 0, stream>>>(
      Wtb, nullptr, 0, KC2_, 0, tT, nullptr, (long)KN_ * KC2_, KC2_,
      out, nullptr, (long)KC2_ * KN_, KN_, KC2_, e6);
}

// Round 12
// 187.939 us; speedup vs baseline: 1.1255x; 1.0180x over previous
//
#include <hip/hip_runtime.h>
#include <cstdint>
#include <cstddef>

// Problem constants (B, C, N fixed by the reference)
#define KB_  8
#define KC_  512
#define KC2_ 256
#define KN_  2048

typedef __attribute__((ext_vector_type(8))) __bf16 bf16x8;
typedef __attribute__((ext_vector_type(8))) unsigned short u16x8;
typedef __attribute__((ext_vector_type(4))) float f32x4;

__device__ __forceinline__ unsigned short f2bf(float f) {
  union { float f; unsigned u; } x; x.f = f;
  unsigned r = x.u + 0x7fffu + ((x.u >> 16) & 1u);  // RNE (finite values only)
  return (unsigned short)(r >> 16);
}
__device__ __forceinline__ float bf2f(unsigned short h) {
  union { unsigned u; float f; } x; x.u = ((unsigned)h) << 16;
  return x.f;
}

// async global->LDS, 16B per lane; LDS dest = wave-uniform base + lane*16 (linear!)
#define GLD16(g, l) __builtin_amdgcn_global_load_lds( \
    (__attribute__((address_space(1))) void*)(g),     \
    (__attribute__((address_space(3))) void*)(l), 16, 0, 0)

// counted-vmcnt barrier pair (T4): wait only the CURRENT buffer's 8 loads;
// next-tile loads stay in flight across the barrier.
#define WAIT_VM8()  asm volatile("s_waitcnt vmcnt(8)" ::: "memory")
#define WAIT_VM0()  asm volatile("s_waitcnt vmcnt(0)" ::: "memory")
#define BARRIER()   __builtin_amdgcn_s_barrier()

// bijective XCD-aware block swizzle (nb % 8 == 0 for all our grids)
__device__ __forceinline__ void xcd_swizzle(int& bx, int& by, int& bz) {
  const int gx = gridDim.x, gy = gridDim.y;
  const int nb = gx * gy * (int)gridDim.z;
  int f = ((int)blockIdx.z * gy + (int)blockIdx.y) * gx + (int)blockIdx.x;
  if ((nb & 7) == 0) f = (f & 7) * (nb >> 3) + (f >> 3);
  const int gxy = gx * gy;
  bz = f / gxy; int rem = f - bz * gxy;
  by = rem / gx; bx = rem - by * gx;
}

// ---------------- all weight conversions in one launch (384 blocks) ----------------
__global__ __launch_bounds__(256) void cvt_all_kernel(
    const float* __restrict__ Wq, const float* __restrict__ Wk,
    const float* __restrict__ Wv, const float* __restrict__ Wt,
    unsigned short* __restrict__ Wqhi, unsigned short* __restrict__ Wqlo,
    unsigned short* __restrict__ Wkhi, unsigned short* __restrict__ Wklo,
    unsigned short* __restrict__ Wvb, unsigned short* __restrict__ Wtb) {
  int blk = blockIdx.x, t = threadIdx.x;
  if (blk < 128) {                     // Wq -> hi/lo pair (131072 elems)
    int i = (blk * 256 + t) * 4;
    float4 f = *(const float4*)(Wq + i);
    ushort4 h = { f2bf(f.x), f2bf(f.y), f2bf(f.z), f2bf(f.w) };
    ushort4 l = { f2bf(f.x - bf2f(h.x)), f2bf(f.y - bf2f(h.y)),
                  f2bf(f.z - bf2f(h.z)), f2bf(f.w - bf2f(h.w)) };
    *(ushort4*)(Wqhi + i) = h; *(ushort4*)(Wqlo + i) = l;
  } else if (blk < 192) {              // Wk -> hi/lo pair (65536)
    int i = ((blk - 128) * 256 + t) * 4;
    float4 f = *(const float4*)(Wk + i);
    ushort4 h = { f2bf(f.x), f2bf(f.y), f2bf(f.z), f2bf(f.w) };
    ushort4 l = { f2bf(f.x - bf2f(h.x)), f2bf(f.y - bf2f(h.y)),
                  f2bf(f.z - bf2f(h.z)), f2bf(f.w - bf2f(h.w)) };
    *(ushort4*)(Wkhi + i) = h; *(ushort4*)(Wklo + i) = l;
  } else if (blk < 320) {              // Wv -> single bf16 (131072)
    int i = ((blk - 192) * 256 + t) * 4;
    float4 f = *(const float4*)(Wv + i);
    ushort4 u = { f2bf(f.x), f2bf(f.y), f2bf(f.z), f2bf(f.w) };
    *(ushort4*)(Wvb + i) = u;
  } else {                             // Wt -> single bf16 (65536)
    int i = ((blk - 320) * 256 + t) * 4;
    float4 f = *(const float4*)(Wt + i);
    ushort4 u = { f2bf(f.x), f2bf(f.y), f2bf(f.z), f2bf(f.w) };
    *(ushort4*)(Wtb + i) = u;
  }
}

// ---------------- merged q/x transpose: fp32 [R][N] -> bf16 hi/lo [N][R] ----------------
// grid (KN/64, 12, KB): by<8 -> q (R=512), else x (R=256)
__global__ __launch_bounds__(256) void transpose2_kernel(
    const float* __restrict__ q, const float* __restrict__ x,
    unsigned short* __restrict__ qThi, unsigned short* __restrict__ qTlo,
    unsigned short* __restrict__ xThi, unsigned short* __restrict__ xTlo) {
  int b = blockIdx.z;
  const float* in; unsigned short *hi, *lo; int R, r0;
  if (blockIdx.y < 8) {
    in = q + (size_t)b * KC_ * KN_;  hi = qThi; lo = qTlo;
    R = KC_;  r0 = blockIdx.y * 64;
    hi += (size_t)b * KN_ * KC_;  lo += (size_t)b * KN_ * KC_;
  } else {
    in = x + (size_t)b * KC2_ * KN_; hi = xThi; lo = xTlo;
    R = KC2_; r0 = (blockIdx.y - 8) * 64;
    hi += (size_t)b * KN_ * KC2_; lo += (size_t)b * KN_ * KC2_;
  }
  __shared__ float tile[64][65];
  int t = threadIdx.x;
  int c0 = blockIdx.x * 64;
#pragma unroll
  for (int k = 0; k < 4; k++) {
    int vi = k * 256 + t, rr = vi >> 4, cv = vi & 15;
    float4 f = *(const float4*)&in[(size_t)(r0 + rr) * KN_ + c0 + cv * 4];
    tile[rr][cv * 4 + 0] = f.x; tile[rr][cv * 4 + 1] = f.y;
    tile[rr][cv * 4 + 2] = f.z; tile[rr][cv * 4 + 3] = f.w;
  }
  __syncthreads();
#pragma unroll
  for (int k = 0; k < 4; k++) {
    int vi = k * 256 + t, cc = vi >> 4, rv = vi & 15;
    float f0 = tile[rv * 4 + 0][cc], f1 = tile[rv * 4 + 1][cc];
    float f2 = tile[rv * 4 + 2][cc], f3 = tile[rv * 4 + 3][cc];
    ushort4 h = { f2bf(f0), f2bf(f1), f2bf(f2), f2bf(f3) };
    ushort4 l = { f2bf(f0 - bf2f(h.x)), f2bf(f1 - bf2f(h.y)),
                  f2bf(f2 - bf2f(h.z)), f2bf(f3 - bf2f(h.w)) };
    size_t o = (size_t)(c0 + cc) * R + r0 + rv * 4;
    *(ushort4*)&hi[o] = h;
    *(ushort4*)&lo[o] = l;
  }
}

// ---------------- rsv[b][n] = 1 / sum_k rowpart[b][n][k] ----------------
__global__ __launch_bounds__(256) void rowreduce_kernel(const float* __restrict__ rowpart,
                                                        float* __restrict__ rsv) {
  int idx = blockIdx.x * 256 + threadIdx.x;  // 8*2048 rows
  const float* p = rowpart + (size_t)idx * 32;
  float s = 0.f;
#pragma unroll
  for (int k = 0; k < 32; k++) s += p[k];
  rsv[idx] = 1.0f / s;
}

// ---------------- energy kernel: 128x128, 4 waves, 2-phase dbuf (counted vmcnt)
//                   split hi/lo GEMM + exp + transpose + row-partials ----
__global__ __launch_bounds__(256) void energy_kernel(
    const unsigned short* __restrict__ Ahi, const unsigned short* __restrict__ Alo,
    const unsigned short* __restrict__ Bhi, const unsigned short* __restrict__ Blo,
    unsigned short* __restrict__ uT, float* __restrict__ rowpart) {
  int bx, by, b;
  xcd_swizzle(bx, by, b);  // grid (16,16,8): each XCD owns one batch
  Ahi += (size_t)b * KN_ * KC2_; Alo += (size_t)b * KN_ * KC2_;
  Bhi += (size_t)b * KN_ * KC2_; Blo += (size_t)b * KN_ * KC2_;
  const int m0 = by * 128;  // rows = n (query idx)
  const int n0 = bx * 128;  // cols = m (key idx)
  __shared__ __align__(16) char smem[65536];  // 2 phases x 32KB; phase0 reused for transpose
  const int t = threadIdx.x, lane = t & 63, w = t >> 6;
  const int wr = w >> 1, wc = w & 1;
  const int srow = t >> 2;
  const int scol = (((t & 3) ^ ((srow >> 1) & 3)) * 8);   // pre-swizzled k-chunk
  const int lr = lane & 15, lk = (lane >> 4) * 8;
  const int rsw = ((lr >> 1) & 3) << 4;                   // read-side XOR (bytes)

  auto STAGE = [&](char* dst, int kt) {
    const size_t ga = (size_t)(m0 + srow) * KC2_ + kt + scol;
    const size_t gb = (size_t)(n0 + srow) * KC2_ + kt + scol;
    GLD16(Ahi + ga, dst + 0 + w * 1024);
    GLD16(Ahi + ga + (size_t)64 * KC2_, dst + 4096 + w * 1024);
    GLD16(Alo + ga, dst + 8192 + w * 1024);
    GLD16(Alo + ga + (size_t)64 * KC2_, dst + 12288 + w * 1024);
    GLD16(Bhi + gb, dst + 16384 + w * 1024);
    GLD16(Bhi + gb + (size_t)64 * KC2_, dst + 20480 + w * 1024);
    GLD16(Blo + gb, dst + 24576 + w * 1024);
    GLD16(Blo + gb + (size_t)64 * KC2_, dst + 28672 + w * 1024);
  };

  f32x4 acc[4][4];
  const f32x4 z = {0.f, 0.f, 0.f, 0.f};
#pragma unroll
  for (int i = 0; i < 4; i++)
#pragma unroll
    for (int j = 0; j < 4; j++) acc[i][j] = z;

  STAGE(smem, 0);
  for (int kt8 = 0; kt8 < 8; kt8++) {
    char* cur = smem + (kt8 & 1) * 32768;
    char* nxt = smem + ((kt8 & 1) ^ 1) * 32768;
    if (kt8 < 7) {
      STAGE(nxt, (kt8 + 1) * 32);  // +8 loads in flight
      WAIT_VM8();                  // wait only cur's 8 (oldest)
    } else {
      WAIT_VM0();
    }
    BARRIER();                     // all waves' cur-loads visible
    bf16x8 ah[4], al[4], bh[4], bl[4];
#pragma unroll
    for (int i = 0; i < 4; i++) {
      int ro = (wr * 64 + i * 16 + lr) * 64 + ((lk * 2) ^ rsw);
      ah[i] = *(const bf16x8*)(cur + 0 + ro);
      al[i] = *(const bf16x8*)(cur + 8192 + ro);
    }
#pragma unroll
    for (int j = 0; j < 4; j++) {
      int ro = (wc * 64 + j * 16 + lr) * 64 + ((lk * 2) ^ rsw);
      bh[j] = *(const bf16x8*)(cur + 16384 + ro);
      bl[j] = *(const bf16x8*)(cur + 24576 + ro);
    }
#pragma unroll
    for (int i = 0; i < 4; i++)
#pragma unroll
      for (int j = 0; j < 4; j++) {
        acc[i][j] = __builtin_amdgcn_mfma_f32_16x16x32_bf16(al[i], bh[j], acc[i][j], 0, 0, 0);
        acc[i][j] = __builtin_amdgcn_mfma_f32_16x16x32_bf16(ah[i], bl[j], acc[i][j], 0, 0, 0);
        acc[i][j] = __builtin_amdgcn_mfma_f32_16x16x32_bf16(ah[i], bh[j], acc[i][j], 0, 0, 0);
      }
    BARRIER();                     // all reads of cur done before it's restaged
  }

  // ---- u = exp(E - 40) ----
#pragma unroll
  for (int i = 0; i < 4; i++)
#pragma unroll
    for (int j = 0; j < 4; j++)
#pragma unroll
      for (int r = 0; r < 4; r++) acc[i][j][r] = __expf(acc[i][j][r] - 40.f);

  // ---- partial row sums ----
#pragma unroll
  for (int i = 0; i < 4; i++) {
#pragma unroll
    for (int r = 0; r < 4; r++) {
      float s = acc[i][0][r] + acc[i][1][r] + acc[i][2][r] + acc[i][3][r];
      s += __shfl_xor(s, 1, 64); s += __shfl_xor(s, 2, 64);
      s += __shfl_xor(s, 4, 64); s += __shfl_xor(s, 8, 64);
      if ((lane & 15) == 0) {
        int row = m0 + wr * 64 + i * 16 + ((lane >> 4) << 2) + r;
        rowpart[((size_t)b * KN_ + row) * 32 + bx * 2 + wc] = s;
      }
    }
  }

  // ---- transpose to uT via LDS (XOR-swizzled banks) ----
#pragma unroll
  for (int i = 0; i < 4; i++) {
#pragma unroll
    for (int j = 0; j < 4; j++) {
#pragma unroll
      for (int r2 = 0; r2 < 4; r2 += 2) {
        int qn = wr * 64 + i * 16 + ((lane >> 4) << 2) + r2;
        int km = wc * 64 + j * 16 + lr;
        unsigned pk = (unsigned)f2bf(acc[i][j][r2]) |
                      ((unsigned)f2bf(acc[i][j][r2 + 1]) << 16);
        int a = ((km << 8) + (qn << 1)) ^ ((km & 15) << 4);
        *(unsigned*)(smem + a) = pk;
      }
    }
  }
  __syncthreads();
  // read 16B per lane, 16 lanes cooperate per uT row -> 256B coalesced bursts
#pragma unroll
  for (int it = 0; it < 8; it++) {
    int km = (t >> 4) + it * 16, chunk = t & 15;
    int a = ((km << 8) + (chunk << 4)) ^ ((km & 15) << 4);
    size_t g = ((size_t)b * KN_ + (n0 + km)) * KN_ + m0 + chunk * 8;
    *(bf16x8*)&uT[g] = *(const bf16x8*)(smem + a);
  }
}

// ---------------- epilogue variants ----------------
enum { EPI_PAIR = 0, EPI_VSCALE = 2, EPI_XRT = 3, EPI_FINAL = 4 };

struct EpiParams {
  const float* bias;
  const float* xf;  long xf_stride;
  const float* scale; long scale_stride;
  const float* rsvp;                    // rsv[b][n] for XRT's fused denom
  const float* gamma; const float* beta; const float* mean; const float* var;
};

// ============== unified MFMA GEMM core, 128x128 tile, BK=64, 2-phase dbuf
// with counted vmcnt; segmented-K: if seg>0 (K=3*seg): A'=[A0|A1|A0], B'=[B0|B0|B1].
// EPI_XRT additionally accumulates ddot[m] = sum_n u[m][n]*rsv[n] from the B
// fragments in the K-loop (fused denom; the read-XOR cancels the staged swizzle,
// so fragment elem e maps to n = t8*64 + kk*32 + lk + e). ====
template<int EPI>
__device__ __forceinline__ void gemm_core(
    char* __restrict__ smem, int bx, int by, int b,
    const unsigned short* __restrict__ A0, const unsigned short* __restrict__ A1,
    long sA, int lda, int seg,
    const unsigned short* __restrict__ B0, const unsigned short* __restrict__ B1,
    long sB, int ldb,
    void* __restrict__ Cv, void* __restrict__ Cv2, long sC, int ldc, int K,
    const EpiParams& ep) {
  A0 += (size_t)b * sA; A1 += (size_t)b * sA;
  B0 += (size_t)b * sB; B1 += (size_t)b * sB;
  const int m0 = by * 128, n0 = bx * 128;
  const int t = threadIdx.x, lane = t & 63, w = t >> 6;
  const int wr = w >> 1, wc = w & 1;
  const int srow = t >> 2;
  const int scol = (((t & 3) ^ ((srow >> 1) & 3)) * 8);   // pre-swizzled k-chunk
  const int lr = lane & 15, lk = (lane >> 4) * 8;
  const int rsw = ((lr >> 1) & 3) << 4;                   // read-side XOR (bytes)

  auto STAGE = [&](char* dst, int kt) {
    int s = seg ? ((kt >= seg) + (kt >= 2 * seg)) : 0;
    int kl = kt - s * seg;
    const unsigned short* Ab = (s == 1) ? A1 : A0;
    const unsigned short* Bb = (s == 2) ? B1 : B0;
    const unsigned short* gA = Ab + (size_t)(m0 + srow) * lda + kl + scol;
    const unsigned short* gB = Bb + (size_t)(n0 + srow) * ldb + kl + scol;
    GLD16(gA, dst + w * 1024);                         // A k0
    GLD16(gA + (size_t)64 * lda, dst + 4096 + w * 1024);
    GLD16(gA + 32, dst + 8192 + w * 1024);             // A k1
    GLD16(gA + (size_t)64 * lda + 32, dst + 12288 + w * 1024);
    GLD16(gB, dst + 16384 + w * 1024);                 // B k0
    GLD16(gB + (size_t)64 * ldb, dst + 20480 + w * 1024);
    GLD16(gB + 32, dst + 24576 + w * 1024);            // B k1
    GLD16(gB + (size_t)64 * ldb + 32, dst + 28672 + w * 1024);
  };

  f32x4 acc[4][4];
  const f32x4 z = {0.f, 0.f, 0.f, 0.f};
#pragma unroll
  for (int i = 0; i < 4; i++)
#pragma unroll
    for (int j = 0; j < 4; j++) acc[i][j] = z;
  float ddot[4] = {0.f, 0.f, 0.f, 0.f};  // XRT only (dead otherwise)

  const int nt = K >> 6;
  STAGE(smem, 0);
  for (int t8 = 0; t8 < nt; t8++) {
    char* cur = smem + (t8 & 1) * 32768;
    char* nxt = smem + ((t8 & 1) ^ 1) * 32768;
    if (t8 < nt - 1) {
      STAGE(nxt, (t8 + 1) * 64);
      WAIT_VM8();
    } else {
      WAIT_VM0();
    }
    BARRIER();
#pragma unroll
    for (int kk = 0; kk < 2; kk++) {
      bf16x8 af[4], bfv[4];
#pragma unroll
      for (int i = 0; i < 4; i++)
        af[i] = *(const bf16x8*)(cur + kk * 8192 +
                                 (wr * 64 + i * 16 + lr) * 64 + ((lk * 2) ^ rsw));
#pragma unroll
      for (int j = 0; j < 4; j++)
        bfv[j] = *(const bf16x8*)(cur + 16384 + kk * 8192 +
                                  (wc * 64 + j * 16 + lr) * 64 + ((lk * 2) ^ rsw));
      if constexpr (EPI == EPI_XRT) {
        const float* Rv = ep.rsvp + (size_t)b * KN_ + t8 * 64 + kk * 32 + lk;
        float4 r0 = *(const float4*)Rv;
        float4 r1 = *(const float4*)(Rv + 4);
#pragma unroll
        for (int j = 0; j < 4; j++) {
          ddot[j] += (float)bfv[j][0] * r0.x + (float)bfv[j][1] * r0.y +
                     (float)bfv[j][2] * r0.z + (float)bfv[j][3] * r0.w +
                     (float)bfv[j][4] * r1.x + (float)bfv[j][5] * r1.y +
                     (float)bfv[j][6] * r1.z + (float)bfv[j][7] * r1.w;
        }
      }
#pragma unroll
      for (int i = 0; i < 4; i++)
#pragma unroll
        for (int j = 0; j < 4; j++)
          acc[i][j] = __builtin_amdgcn_mfma_f32_16x16x32_bf16(af[i], bfv[j], acc[i][j], 0, 0, 0);
    }
    BARRIER();
  }

  if constexpr (EPI == EPI_XRT) {
    // finish fused denom: reduce ddot over the 4 lk-groups (lanes lane^16, lane^32)
    float dinv[4];
#pragma unroll
    for (int j = 0; j < 4; j++) {
      float d = ddot[j];
      d += __shfl_xor(d, 16, 64);
      d += __shfl_xor(d, 32, 64);
      dinv[j] = 1.0f / (1e-9f + d);
    }
    // t[c][m] = x[c][m] - acc*dinv[m]; transpose in LDS -> tT[m][c] (bf16)
    const float* X = ep.xf + (size_t)b * ep.xf_stride;
#pragma unroll
    for (int i = 0; i < 4; i++) {
#pragma unroll
      for (int j = 0; j < 4; j++) {
#pragma unroll
        for (int r2 = 0; r2 < 4; r2 += 2) {
          int cl = wr * 64 + i * 16 + ((lane >> 4) << 2) + r2;
          int ml = wc * 64 + j * 16 + lr;
          float x0 = X[(size_t)(m0 + cl) * KN_ + n0 + ml];
          float x1 = X[(size_t)(m0 + cl + 1) * KN_ + n0 + ml];
          float t0 = x0 - acc[i][j][r2] * dinv[j];
          float t1 = x1 - acc[i][j][r2 + 1] * dinv[j];
          unsigned pk = (unsigned)f2bf(t0) | ((unsigned)f2bf(t1) << 16);
          int a = ((ml << 8) + (cl << 1)) ^ ((ml & 15) << 4);
          *(unsigned*)(smem + a) = pk;
        }
      }
    }
    __syncthreads();
    unsigned short* tT = (unsigned short*)Cv;
#pragma unroll
    for (int it = 0; it < 8; it++) {
      int ml = (t >> 4) + it * 16, chunk = t & 15;
      int a = ((ml << 8) + (chunk << 4)) ^ ((ml & 15) << 4);
      size_t g = ((size_t)b * KN_ + (n0 + ml)) * KC2_ + m0 + chunk * 8;
      *(bf16x8*)&tT[g] = *(const bf16x8*)(smem + a);
    }
    return;
  }

#pragma unroll
  for (int i = 0; i < 4; i++) {
#pragma unroll
    for (int r = 0; r < 4; r++) {
      const int row = m0 + wr * 64 + i * 16 + ((lane >> 4) << 2) + r;
      float pbias = 0.f, pinv = 1.f, padd = 0.f;
      if constexpr (EPI == EPI_VSCALE) pbias = ep.bias[row];
      if constexpr (EPI == EPI_FINAL) {
        pbias = ep.bias[row];
        float iv = ep.gamma[row] * rsqrtf(ep.var[row] + 1e-5f);
        pinv = iv;
        padd = ep.beta[row] - ep.mean[row] * iv;
      }
#pragma unroll
      for (int j = 0; j < 4; j++) {
        const int col = n0 + wc * 64 + j * 16 + lr;
        float v = acc[i][j][r];
        size_t o = (size_t)b * sC + (size_t)row * ldc + col;
        if constexpr (EPI == EPI_PAIR) {
          unsigned short h = f2bf(v);
          ((unsigned short*)Cv)[o] = h;
          ((unsigned short*)Cv2)[o] = f2bf(v - bf2f(h));
        } else if constexpr (EPI == EPI_VSCALE) {
          float sc = ep.scale[(size_t)b * ep.scale_stride + col];
          ((unsigned short*)Cv)[o] = f2bf((v + pbias) * sc);
        } else {  // EPI_FINAL
          float h = (v + pbias) * pinv + padd;
          h = fmaxf(h, 0.f);
          float xval = ep.xf[(size_t)b * ep.xf_stride + o - (size_t)b * sC];
          ((float*)Cv)[o] = h + xval;
        }
      }
    }
  }
}

// generic single-GEMM kernel (64 KB LDS, 2-phase)
template<int EPI>
__global__ __launch_bounds__(256) void gemm_one(
    const unsigned short* __restrict__ A0, const unsigned short* __restrict__ A1,
    long sA, int lda, int seg,
    const unsigned short* __restrict__ B0, const unsigned short* __restrict__ B1,
    long sB, int ldb,
    void* __restrict__ Cv, void* __restrict__ Cv2, long sC, int ldc, int K,
    EpiParams ep) {
  __shared__ __align__(16) char smem[65536];
  int bx, by, b;
  xcd_swizzle(bx, by, b);
  gemm_core<EPI>(smem, bx, by, b, A0, A1, sA, lda, seg, B0, B1, sB, ldb,
                 Cv, Cv2, sC, ldc, K, ep);
}

// fused x_q + x_k projections: one 512-block launch
__global__ __launch_bounds__(256) void proj2_kernel(
    const unsigned short* __restrict__ qThi, const unsigned short* __restrict__ qTlo,
    const unsigned short* __restrict__ Wqhi, const unsigned short* __restrict__ Wqlo,
    unsigned short* __restrict__ xqhi, unsigned short* __restrict__ xqlo,
    const unsigned short* __restrict__ xThi, const unsigned short* __restrict__ xTlo,
    const unsigned short* __restrict__ Wkhi, const unsigned short* __restrict__ Wklo,
    unsigned short* __restrict__ xkhi, unsigned short* __restrict__ xklo) {
  __shared__ __align__(16) char smem[65536];
  int f = (int)blockIdx.x;
  f = (f & 7) * 64 + (f >> 3);  // XCD swizzle over 512
  EpiParams ep{};
  if (f < 256) {
    int bx = f & 1, by = (f >> 1) & 15, b = f >> 5;
    gemm_core<EPI_PAIR>(smem, bx, by, b, qThi, qTlo, (long)KN_ * KC_, KC_, KC_,
                        Wqhi, Wqlo, 0, KC_, xqhi, xqlo, (long)KN_ * KC2_, KC2_,
                        3 * KC_, ep);
  } else {
    int g = f - 256;
    int bx = g & 1, by = (g >> 1) & 15, b = g >> 5;
    gemm_core<EPI_PAIR>(smem, bx, by, b, xThi, xTlo, (long)KN_ * KC2_, KC2_, KC2_,
                        Wkhi, Wklo, 0, KC2_, xkhi, xklo, (long)KN_ * KC2_, KC2_,
                        3 * KC2_, ep);
  }
}

// ---------------- launcher ----------------
extern "C" void kernel_launch(void* const* d_in, const int* in_sizes, int n_in,
                              void* d_out, int out_size, void* d_ws, size_t ws_size,
                              hipStream_t stream) {
  (void)in_sizes; (void)n_in; (void)out_size; (void)ws_size;
  const float* q     = (const float*)d_in[0];
  const float* x     = (const float*)d_in[1];
  const float* Wq    = (const float*)d_in[2];
  const float* Wk    = (const float*)d_in[3];
  const float* Wv    = (const float*)d_in[4];
  const float* bv    = (const float*)d_in[5];
  const float* Wt    = (const float*)d_in[6];
  const float* bt    = (const float*)d_in[7];
  const float* gamma = (const float*)d_in[8];
  const float* beta  = (const float*)d_in[9];
  const float* rmean = (const float*)d_in[10];
  const float* rvar  = (const float*)d_in[11];
  float* out = (float*)d_out;

  // workspace (~164 MiB)
  const size_t SZ_qT = (size_t)KB_ * KN_ * KC_ * 2;   // 16 MiB
  const size_t SZ_xT = (size_t)KB_ * KN_ * KC2_ * 2;  //  8 MiB
  char* ws = (char*)d_ws;
  size_t off = 0;
  auto alloc = [&](size_t bytes) {
    char* p = ws + off;
    off += (bytes + 255) & ~(size_t)255;
    return p;
  };
  unsigned short* qThi = (unsigned short*)alloc(SZ_qT);
  unsigned short* qTlo = (unsigned short*)alloc(SZ_qT);
  unsigned short* xThi = (unsigned short*)alloc(SZ_xT);
  unsigned short* xTlo = (unsigned short*)alloc(SZ_xT);
  unsigned short* xqhi = (unsigned short*)alloc(SZ_xT);
  unsigned short* xqlo = (unsigned short*)alloc(SZ_xT);
  unsigned short* xkhi = (unsigned short*)alloc(SZ_xT);
  unsigned short* xklo = (unsigned short*)alloc(SZ_xT);
  unsigned short* x_v  = (unsigned short*)alloc((size_t)KB_ * KC2_ * KN_ * 2);
  unsigned short* tT   = (unsigned short*)alloc(SZ_xT);
  unsigned short* Wqhi = (unsigned short*)alloc((size_t)KC2_ * KC_ * 2);
  unsigned short* Wqlo = (unsigned short*)alloc((size_t)KC2_ * KC_ * 2);
  unsigned short* Wkhi = (unsigned short*)alloc((size_t)KC2_ * KC2_ * 2);
  unsigned short* Wklo = (unsigned short*)alloc((size_t)KC2_ * KC2_ * 2);
  unsigned short* Wvb  = (unsigned short*)alloc((size_t)KC2_ * KC_ * 2);
  unsigned short* Wtb  = (unsigned short*)alloc((size_t)KC2_ * KC2_ * 2);
  float* rsv     = (float*)alloc((size_t)KB_ * KN_ * 4);
  float* rowpart = (float*)alloc((size_t)KB_ * KN_ * 32 * 4);
  unsigned short* uT = (unsigned short*)alloc((size_t)KB_ * KN_ * KN_ * 2);   // 64 MiB

  dim3 blk(256);

  // all weight conversions (one launch)
  cvt_all_kernel<<<dim3(384), blk, 0, stream>>>(Wq, Wk, Wv, Wt,
                                                Wqhi, Wqlo, Wkhi, Wklo, Wvb, Wtb);

  // q^T and x^T in one launch: fp32 -> hi/lo bf16 pairs (K contiguous)
  transpose2_kernel<<<dim3(KN_ / 64, 12, KB_), blk, 0, stream>>>(
      q, x, qThi, qTlo, xThi, xTlo);

  // x_q / x_kT projections (fp32-grade via segmented-K)
  proj2_kernel<<<dim3(512), blk, 0, stream>>>(qThi, qTlo, Wqhi, Wqlo, xqhi, xqlo,
                                              xThi, xTlo, Wkhi, Wklo, xkhi, xklo);

  // energy + exp + transpose + row partials (2-phase dbuf, counted vmcnt)
  energy_kernel<<<dim3(KN_ / 128, KN_ / 128, KB_), blk, 0, stream>>>(
      xqhi, xqlo, xkhi, xklo, uT, rowpart);
  rowreduce_kernel<<<dim3(KB_ * KN_ / 256), blk, 0, stream>>>(rowpart, rsv);

  // x_v'[b][o][n] = (Wv[o][:].qT[n][:] + bv[o]) * rsv[b][n]
  EpiParams e3{}; e3.bias = bv; e3.scale = rsv; e3.scale_stride = KN_;
  gemm_one<EPI_VSCALE><<<dim3(KN_ / 128, KC2_ / 128, KB_), blk, 0, stream>>>(
      Wvb, nullptr, 0, KC_, 0, qThi, nullptr, (long)KN_ * KC_, KC_,
      x_v, nullptr, (long)KC2_ * KN_, KN_, KC_, e3);

  // x_r GEMM with fused denom + renorm + subtract + transpose -> tT[m][c]
  EpiParams e5{}; e5.xf = x; e5.xf_stride = (long)KC2_ * KN_;
  e5.rsvp = rsv;
  gemm_one<EPI_XRT><<<dim3(KN_ / 128, KC2_ / 128, KB_), blk, 0, stream>>>(
      x_v, nullptr, (long)KC2_ * KN_, KN_, 0, uT, nullptr, (long)KN_ * KN_, KN_,
      tT, nullptr, 0, 0, KN_, e5);

  // out[b][o][n] = relu(BN(Wt[o][:].tT[n][:] + bt[o])) + x[b][o][n]
  EpiParams e6{}; e6.bias = bt; e6.xf = x; e6.xf_stride = (long)KC2_ * KN_;
  e6.gamma = gamma; e6.beta = beta; e6.mean = rmean; e6.var = rvar;
  gemm_one<EPI_FINAL><<<dim3(KN_ / 128, KC2_ / 128, KB_), blk, 0, stream>>>(
      Wtb, nullptr, 0, KC2_, 0, tT, nullptr, (long)KN_ * KC2_, KC2_,
      out, nullptr, (long)KC2_ * KN_, KN_, KC2_, e6);
}